// Round 1
// baseline (130.993 us; speedup 1.0000x reference)
//
#include <hip/hip_runtime.h>

// ContrasPQ forward = per-(b,p) nearest-code lookup.
// out[b, p*8 .. p*8+7] = codebook[p, argmin_k ||v[b,p]-c[p,k]||^2, :]
// argmin via s_k = sum_d (-2*c_kd)*v_d + ||c_k||^2 (drops ||v||^2, constant
// in k). Strict-less update over ascending k == jnp.argmax first-index
// tie-break.
//
// R1: inner dot rewritten as 4x v_pk_fma_f32 (VOP3P packed fp32, 2 FMA/instr)
// + 1 v_add_f32 horizontal combine. Cuts per-(k,q) VALU issue 11 -> 8.
// ||c||^2 stored in LDS as {c2, 0} float2 so the packed accumulator init is a
// single ds_read_b64 (no per-k pair-building movs).

#define TPB 256   // threads per block
#define KBQ 4     // queries (b rows) per thread

typedef float f32x2 __attribute__((ext_vector_type(2)));
typedef float f32x4 __attribute__((ext_vector_type(4)));

namespace {
constexpr int kB   = 8192;
constexpr int kEMB = 768;
constexpr int kP   = 96;
constexpr int kK   = 256;
constexpr int kD   = 8;
}

__device__ __forceinline__ f32x2 pk_fma(f32x2 a, f32x2 b, f32x2 c)
{
    f32x2 d;
    // D.lo = A.lo*B.lo + C.lo ; D.hi = A.hi*B.hi + C.hi  (even-aligned pairs)
    asm("v_pk_fma_f32 %0, %1, %2, %3" : "=v"(d) : "v"(a), "v"(b), "v"(c));
    return d;
}

__global__ __launch_bounds__(TPB, 3)
void pq_argmin_kernel(const float* __restrict__ vecs,
                      const float* __restrict__ codebook,
                      float* __restrict__ out)
{
    // codebook slice for this p, pre-scaled by -2 (8 KB), plus {||c||^2, 0}
    // pairs (2 KB) for direct b64 read into the packed accumulator.
    __shared__ alignas(16) float lds_code[kK][kD];
    __shared__ alignas(16) f32x2 lds_c2[kK];

    const int p = blockIdx.y;
    const int t = threadIdx.x;

    // ---- stage codebook[p] into LDS (coalesced: thread t loads code t) ----
    {
        const f32x4* cb4 =
            reinterpret_cast<const f32x4*>(codebook + (size_t)p * kK * kD);
        f32x4 a = cb4[2 * t];
        f32x4 b = cb4[2 * t + 1];
        float c2 = a.x * a.x + a.y * a.y + a.z * a.z + a.w * a.w +
                   b.x * b.x + b.y * b.y + b.z * b.z + b.w * b.w;
        f32x4* lc = reinterpret_cast<f32x4*>(&lds_code[t][0]);
        lc[0] = f32x4{-2.0f * a.x, -2.0f * a.y, -2.0f * a.z, -2.0f * a.w};
        lc[1] = f32x4{-2.0f * b.x, -2.0f * b.y, -2.0f * b.z, -2.0f * b.w};
        lds_c2[t] = f32x2{c2, 0.0f};
    }
    __syncthreads();

    // ---- load KBQ query subvectors (8 floats each, 2x dwordx4) ----
    const int b0 = blockIdx.x * (TPB * KBQ) + t;

    f32x2 v2[KBQ][4];
#pragma unroll
    for (int q = 0; q < KBQ; ++q) {
        const f32x4* vp = reinterpret_cast<const f32x4*>(
            vecs + (size_t)(b0 + q * TPB) * kEMB + p * kD);
        f32x4 x = vp[0];
        f32x4 y = vp[1];
        v2[q][0] = x.xy;
        v2[q][1] = x.zw;
        v2[q][2] = y.xy;
        v2[q][3] = y.zw;
    }

    float best[KBQ];
    int   bidx[KBQ];
#pragma unroll
    for (int q = 0; q < KBQ; ++q) {
        best[q] = __builtin_inff();
        bidx[q] = 0;
    }

    // ---- main loop: 256 codes, LDS broadcast reads, 4 queries/thread ----
    // per (k,q): 4 pk_fma + 1 add + cmp + 2 cndmask = 8 VALU (was 11)
#pragma unroll 4
    for (int k = 0; k < kK; ++k) {
        const f32x4 c0  = *reinterpret_cast<const f32x4*>(&lds_code[k][0]);
        const f32x4 c1  = *reinterpret_cast<const f32x4*>(&lds_code[k][4]);
        const f32x2 c2k = lds_c2[k];          // {||c_k||^2, 0}
        const f32x2 a01 = c0.xy;
        const f32x2 a23 = c0.zw;
        const f32x2 a45 = c1.xy;
        const f32x2 a67 = c1.zw;
#pragma unroll
        for (int q = 0; q < KBQ; ++q) {
            f32x2 s2 = pk_fma(a01, v2[q][0], c2k);
            s2 = pk_fma(a23, v2[q][1], s2);
            s2 = pk_fma(a45, v2[q][2], s2);
            s2 = pk_fma(a67, v2[q][3], s2);
            float s = s2.x + s2.y;
            if (s < best[q]) {   // strict <: ties keep lower k (ref argmax)
                best[q] = s;
                bidx[q] = k;
            }
        }
    }

    // ---- epilogue: gather winning codebook rows (L2-hot) and store ----
#pragma unroll
    for (int q = 0; q < KBQ; ++q) {
        const f32x4* cr = reinterpret_cast<const f32x4*>(
            codebook + ((size_t)p * kK + bidx[q]) * kD);
        f32x4 r0 = cr[0];
        f32x4 r1 = cr[1];
        f32x4* op = reinterpret_cast<f32x4*>(
            out + (size_t)(b0 + q * TPB) * kEMB + p * kD);
        op[0] = r0;
        op[1] = r1;
    }
}

extern "C" void kernel_launch(void* const* d_in, const int* in_sizes, int n_in,
                              void* d_out, int out_size, void* d_ws, size_t ws_size,
                              hipStream_t stream)
{
    const float* vecs     = (const float*)d_in[0];
    const float* codebook = (const float*)d_in[1];
    float* out            = (float*)d_out;

    dim3 grid(kB / (TPB * KBQ), kP, 1);  // (8, 96)
    dim3 block(TPB, 1, 1);
    hipLaunchKernelGGL(pq_argmin_kernel, grid, block, 0, stream,
                       vecs, codebook, out);
}

// Round 2
// 120.001 us; speedup vs baseline: 1.0916x; 1.0916x over previous
//
#include <hip/hip_runtime.h>

// ContrasPQ forward = per-(b,p) nearest-code lookup.
// out[b, p*8 .. p*8+7] = codebook[p, argmin_k ||v[b,p]-c[p,k]||^2, :]
// argmin via s_k = sum_d (-2*c_kd)*v_d + ||c_k||^2 (drops ||v||^2, constant
// in k). Strict-less update over ascending k == jnp.argmax first-index
// tie-break.
//
// R1 post-mortem: v_pk_fma_f32 is half-rate on gfx950 (157 TF spec = scalar
// rate) -> packed fp32 reverted. Counter arithmetic showed VALUBusy uses the
// gfx94x 4-cyc/wave-instr formula; real pipe occupancy of the 64.5 us kernel
// was ~43% -> latency-stalled at 3 blocks/CU (grid-pinned, 768 blocks).
//
// R2: KBQ 4->2. Grid 768 -> 1536 blocks = 6 blocks/CU = 24 waves/CU. Same
// minimal scalar-FMA body (11 VALU per (k,q)); 2x the independent FMA chains
// per SIMD to cover the ~4-cyc dependent-FMA latency.

#define TPB 256   // threads per block
#define KBQ 2     // queries (b rows) per thread

namespace {
constexpr int kB   = 8192;
constexpr int kEMB = 768;
constexpr int kP   = 96;
constexpr int kK   = 256;
constexpr int kD   = 8;
}

__global__ __launch_bounds__(TPB, 6)
void pq_argmin_kernel(const float* __restrict__ vecs,
                      const float* __restrict__ codebook,
                      float* __restrict__ out)
{
    // codebook slice for this p, pre-scaled by -2, plus ||c||^2 (9 KB LDS)
    __shared__ alignas(16) float lds_code[kK][kD];
    __shared__ alignas(16) float lds_c2[kK];

    const int p = blockIdx.y;
    const int t = threadIdx.x;

    // ---- stage codebook[p] into LDS (coalesced: thread t loads code t) ----
    {
        const float4* cb4 =
            reinterpret_cast<const float4*>(codebook + (size_t)p * kK * kD);
        float4 a = cb4[2 * t];
        float4 b = cb4[2 * t + 1];
        float c2 = a.x * a.x + a.y * a.y + a.z * a.z + a.w * a.w +
                   b.x * b.x + b.y * b.y + b.z * b.z + b.w * b.w;
        float4* lc = reinterpret_cast<float4*>(&lds_code[t][0]);
        lc[0] = make_float4(-2.0f * a.x, -2.0f * a.y, -2.0f * a.z, -2.0f * a.w);
        lc[1] = make_float4(-2.0f * b.x, -2.0f * b.y, -2.0f * b.z, -2.0f * b.w);
        lds_c2[t] = c2;
    }
    __syncthreads();

    // ---- load KBQ query subvectors (8 floats each, 2x float4) ----
    const int b0 = blockIdx.x * (TPB * KBQ) + t;

    float v[KBQ][kD];
#pragma unroll
    for (int q = 0; q < KBQ; ++q) {
        const float4* vp = reinterpret_cast<const float4*>(
            vecs + (size_t)(b0 + q * TPB) * kEMB + p * kD);
        float4 x = vp[0];
        float4 y = vp[1];
        v[q][0] = x.x; v[q][1] = x.y; v[q][2] = x.z; v[q][3] = x.w;
        v[q][4] = y.x; v[q][5] = y.y; v[q][6] = y.z; v[q][7] = y.w;
    }

    float best[KBQ];
    int   bidx[KBQ];
#pragma unroll
    for (int q = 0; q < KBQ; ++q) {
        best[q] = __builtin_inff();
        bidx[q] = 0;
    }

    // ---- main loop: 256 codes, LDS broadcast reads, 2 queries/thread ----
#pragma unroll 4
    for (int k = 0; k < kK; ++k) {
        const float4 c0  = *reinterpret_cast<const float4*>(&lds_code[k][0]);
        const float4 c1  = *reinterpret_cast<const float4*>(&lds_code[k][4]);
        const float  c2k = lds_c2[k];
#pragma unroll
        for (int q = 0; q < KBQ; ++q) {
            float s = fmaf(c0.x, v[q][0], c2k);
            s = fmaf(c0.y, v[q][1], s);
            s = fmaf(c0.z, v[q][2], s);
            s = fmaf(c0.w, v[q][3], s);
            s = fmaf(c1.x, v[q][4], s);
            s = fmaf(c1.y, v[q][5], s);
            s = fmaf(c1.z, v[q][6], s);
            s = fmaf(c1.w, v[q][7], s);
            if (s < best[q]) {   // strict <: ties keep lower k (ref argmax)
                best[q] = s;
                bidx[q] = k;
            }
        }
    }

    // ---- epilogue: gather winning codebook rows (L2-hot) and store ----
#pragma unroll
    for (int q = 0; q < KBQ; ++q) {
        const float4* cr = reinterpret_cast<const float4*>(
            codebook + ((size_t)p * kK + bidx[q]) * kD);
        float4 r0 = cr[0];
        float4 r1 = cr[1];
        float4* op = reinterpret_cast<float4*>(
            out + (size_t)(b0 + q * TPB) * kEMB + p * kD);
        op[0] = r0;
        op[1] = r1;
    }
}

extern "C" void kernel_launch(void* const* d_in, const int* in_sizes, int n_in,
                              void* d_out, int out_size, void* d_ws, size_t ws_size,
                              hipStream_t stream)
{
    const float* vecs     = (const float*)d_in[0];
    const float* codebook = (const float*)d_in[1];
    float* out            = (float*)d_out;

    dim3 grid(kB / (TPB * KBQ), kP, 1);  // (16, 96)
    dim3 block(TPB, 1, 1);
    hipLaunchKernelGGL(pq_argmin_kernel, grid, block, 0, stream,
                       vecs, codebook, out);
}